// Round 3
// baseline (687.580 us; speedup 1.0000x reference)
//
#include <hip/hip_runtime.h>

#define B_ 8
#define CQ_ 256
#define CKV_ 512
#define N_ 4096
#define DQK_ 32

typedef __bf16 bf16;
typedef __bf16 bf16x4 __attribute__((ext_vector_type(4)));
typedef __bf16 bf16x8 __attribute__((ext_vector_type(8)));
typedef float f32x4 __attribute__((ext_vector_type(4)));

// ---------------- weight convert fp32 -> bf16 ----------------
__global__ void k_convert_w(const float* __restrict__ Wq, const float* __restrict__ Wk,
                            const float* __restrict__ Wv,
                            bf16* __restrict__ wq, bf16* __restrict__ wk, bf16* __restrict__ wv) {
    int i = blockIdx.x * 256 + threadIdx.x;
    if (i < 8192) wq[i] = (bf16)Wq[i];
    else if (i < 24576) wk[i - 8192] = (bf16)Wk[i - 8192];
    else if (i < 155648) wv[i - 24576] = (bf16)Wv[i - 24576];
}

// ---------------- bilinear resize 32x32 -> 64x64, transposed to [b][n][u] ----------------
__global__ __launch_bounds__(256) void k_resize(const float* __restrict__ kv, bf16* __restrict__ kvr) {
    const int yo = blockIdx.x;   // output row 0..63
    const int b  = blockIdx.y;
    const int tid = threadIdx.x;
    __shared__ float r0[64][33];
    __shared__ float r1[64][33];
    int ty = yo >> 1;
    int y0, y1; float wy0, wy1;
    if ((yo & 1) == 0) { y0 = ty > 0 ? ty - 1 : 0; y1 = ty; wy0 = 0.25f; wy1 = 0.75f; }
    else               { y0 = ty; y1 = ty < 31 ? ty + 1 : 31; wy0 = 0.75f; wy1 = 0.25f; }
    const int u_loc = tid & 63;
    const int xo_base = tid >> 6;
    for (int uc = 0; uc < CKV_; uc += 64) {
        __syncthreads();
        for (int i = 0; i < 8; ++i) {
            int idx = tid + i * 256;
            int u = idx >> 5, x = idx & 31;
            const float* src = kv + ((size_t)b * CKV_ + uc + u) * 1024 + x;
            r0[u][x] = src[y0 * 32];
            r1[u][x] = src[y1 * 32];
        }
        __syncthreads();
        for (int i = 0; i < 16; ++i) {
            int xo = xo_base + i * 4;
            int tx = xo >> 1;
            int xa, xb; float wxa, wxb;
            if ((xo & 1) == 0) { xa = tx > 0 ? tx - 1 : 0; xb = tx; wxa = 0.25f; wxb = 0.75f; }
            else               { xa = tx; xb = tx < 31 ? tx + 1 : 31; wxa = 0.75f; wxb = 0.25f; }
            float v0 = wxa * r0[u_loc][xa] + wxb * r0[u_loc][xb];
            float v1 = wxa * r1[u_loc][xa] + wxb * r1[u_loc][xb];
            float val = wy0 * v0 + wy1 * v1;
            kvr[((size_t)b * N_ + yo * 64 + xo) * CKV_ + uc + u_loc] = (bf16)val;
        }
    }
}

// ---------------- fused: transpose query tile to LDS + q projection ----------------
__global__ __launch_bounds__(256) void k_proj_q_fused(const float* __restrict__ query,
                                                      const bf16* __restrict__ W,     // [32][256]
                                                      const float* __restrict__ bias, // [32]
                                                      bf16* __restrict__ qTb) {       // [B][N][32]
    __shared__ bf16 tile[64][264];   // [n][c], row stride 528B (16B-aligned)
    const int n0 = blockIdx.x * 64;
    const int b  = blockIdx.y;
    const int tid = threadIdx.x;
    const int xi = tid & 15, c0 = tid >> 4;
    for (int pass = 0; pass < 16; ++pass) {
        int c = c0 + pass * 16;
        const float4 v = *(const float4*)(query + ((size_t)b * CQ_ + c) * N_ + n0 + xi * 4);
        tile[xi * 4 + 0][c] = (bf16)v.x;
        tile[xi * 4 + 1][c] = (bf16)v.y;
        tile[xi * 4 + 2][c] = (bf16)v.z;
        tile[xi * 4 + 3][c] = (bf16)v.w;
    }
    __syncthreads();
    const int w = tid >> 6, lane = tid & 63;
    const int l16 = lane & 15, quad = lane >> 4;
    const int ct = w & 1, nh = w >> 1;
    f32x4 acc[2];
    acc[0] = (f32x4){0.f, 0.f, 0.f, 0.f}; acc[1] = (f32x4){0.f, 0.f, 0.f, 0.f};
    const bf16* aptr = W + (ct * 16 + l16) * CQ_ + quad * 8;
#pragma unroll
    for (int ks = 0; ks < 8; ++ks) {
        bf16x8 af = *(const bf16x8*)(aptr + ks * 32);
        for (int j = 0; j < 2; ++j) {
            bf16x8 bfv = *(const bf16x8*)&tile[nh * 32 + j * 16 + l16][ks * 32 + quad * 8];
            acc[j] = __builtin_amdgcn_mfma_f32_16x16x32_bf16(af, bfv, acc[j], 0, 0, 0);
        }
    }
    for (int j = 0; j < 2; ++j)
        for (int r = 0; r < 4; ++r) {
            int d = ct * 16 + quad * 4 + r;
            int n = n0 + nh * 32 + j * 16 + l16;
            qTb[((size_t)b * N_ + n) * DQK_ + d] = (bf16)(acc[j][r] + bias[d]);
        }
}

// ---------------- k projection ----------------
__global__ __launch_bounds__(256) void k_proj_k(const bf16* __restrict__ W,     // [32][512]
                                                const float* __restrict__ bias, // [32]
                                                const bf16* __restrict__ Bm,    // [B][N][512]
                                                bf16* __restrict__ outT) {      // [B][N][32]
    const int mb = blockIdx.x * 128;
    const int b  = blockIdx.y;
    const int tid = threadIdx.x;
    const int w = tid >> 6, lane = tid & 63;
    const int l16 = lane & 15, quad = lane >> 4;
    const int ct = w & 1;
    const int mhalf = (w >> 1) * 64;
    f32x4 acc[4];
    for (int j = 0; j < 4; ++j) acc[j] = (f32x4){0.f, 0.f, 0.f, 0.f};
    const bf16* aptr  = W + (ct * 16 + l16) * CKV_ + quad * 8;
    const bf16* bbase = Bm + ((size_t)b * N_ + mb + mhalf) * CKV_ + quad * 8;
#pragma unroll
    for (int ks = 0; ks < 16; ++ks) {
        bf16x8 af = *(const bf16x8*)(aptr + ks * 32);
        for (int j = 0; j < 4; ++j) {
            bf16x8 bfv = *(const bf16x8*)(bbase + (size_t)(j * 16 + l16) * CKV_ + ks * 32);
            acc[j] = __builtin_amdgcn_mfma_f32_16x16x32_bf16(af, bfv, acc[j], 0, 0, 0);
        }
    }
    for (int j = 0; j < 4; ++j)
        for (int r = 0; r < 4; ++r) {
            int d = ct * 16 + quad * 4 + r;
            int m = mb + mhalf + j * 16 + l16;
            outT[((size_t)b * N_ + m) * DQK_ + d] = (bf16)(acc[j][r] + bias[d]);
        }
}

// ---------------- v projection ----------------
__global__ __launch_bounds__(256) void k_proj_v(const bf16* __restrict__ W,     // [256][512]
                                                const float* __restrict__ bias, // [256]
                                                const bf16* __restrict__ Bm,    // [B][N][512]
                                                bf16* __restrict__ vout) {      // [B][256][N]
    const int mb = blockIdx.x * 64;
    const int b  = blockIdx.y;
    const int tid = threadIdx.x;
    const int w = tid >> 6, lane = tid & 63;
    const int l16 = lane & 15, quad = lane >> 4;
    f32x4 acc[4][4];
    for (int i = 0; i < 4; ++i) for (int j = 0; j < 4; ++j) acc[i][j] = (f32x4){0.f, 0.f, 0.f, 0.f};
    const bf16* bbase = Bm + ((size_t)b * N_ + mb) * CKV_ + quad * 8;
#pragma unroll 4
    for (int ks = 0; ks < 16; ++ks) {
        bf16x8 bfv[4];
        for (int j = 0; j < 4; ++j)
            bfv[j] = *(const bf16x8*)(bbase + (size_t)(j * 16 + l16) * CKV_ + ks * 32);
        for (int i = 0; i < 4; ++i) {
            bf16x8 af = *(const bf16x8*)(W + (size_t)((w * 4 + i) * 16 + l16) * CKV_ + ks * 32 + quad * 8);
            for (int j = 0; j < 4; ++j)
                acc[i][j] = __builtin_amdgcn_mfma_f32_16x16x32_bf16(af, bfv[j], acc[i][j], 0, 0, 0);
        }
    }
    for (int i = 0; i < 4; ++i)
        for (int r = 0; r < 4; ++r) {
            int c = (w * 4 + i) * 16 + quad * 4 + r;
            float bvs = bias[c];
            for (int j = 0; j < 4; ++j) {
                int m = mb + j * 16 + l16;
                vout[((size_t)b * CQ_ + c) * N_ + m] = (bf16)(acc[i][j][r] + bvs);
            }
        }
}

// ---------------- flash attention: ZERO barriers, fully independent waves ----------------
// Rounds 1-2 showed the binding constraint is the per-iteration cross-wave
// rendezvous (barrier + implicit vmcnt(0)/lgkmcnt(0) drain) at 2 waves/SIMD:
// issue work sums to ~2K cyc/round but rounds took 6.3K. This version
// re-partitions PV so each wave owns 16 n-cols x ALL 256 channels; then the
// P tile a wave consumes is exactly the one it produced. P round-trips
// through a WAVE-PRIVATE double-buffered LDS region (DS ops are in-order per
// wave; proven in the round-0 kernel) -> no __syncthreads anywhere. Same
// MFMA/exp count per wave as round-1 (4 S + 32 PV, 16 exp per iter); V loads
// 4x per wave but identical across the block's 4 waves (L1-shared), and the
// batch<->XCD block remap (b = flat%8, matching the round-robin dispatch)
// makes each batch's V (2MB) + K L2-resident on one XCD.
// P row layout (row = n = l16, 64 m elems, XOR-swizzled by (l16&7)<<3):
//   write (im,q):  elem (im*16+q*4) ^ swz   <- S D-layout m = im*16+q*4+r
//   read  (ks,q):  elem (ks*32+q*8) ^ swz   -> B-frag m = ks*32+q*8+e
// (same per-lane m mapping as the verified round-1 formulas).
__global__ __launch_bounds__(256) void k_flash(const bf16* __restrict__ qT,   // [B][N][32]
                                               const bf16* __restrict__ kT,   // [B][N][32]
                                               const bf16* __restrict__ vv,   // [B][256][N]
                                               const float* __restrict__ query,
                                               const float* __restrict__ gamma,
                                               float* __restrict__ out) {
    __shared__ bf16 P[4][2][16][64];   // per-wave private, double-buffered: 16 KiB
    const int tid = threadIdx.x;
    const int w = tid >> 6, lane = tid & 63;
    const int l16 = lane & 15, quad = lane >> 4;
    const int swz = (l16 & 7) << 3;    // elem-granularity XOR (bits 3..5)
    // batch<->XCD remap: blocks with flat%8==b all process batch b and land on
    // one XCD under round-robin dispatch -> V/K of the batch are L2-resident.
    const int flat = blockIdx.x + 64 * blockIdx.y;
    const int b  = flat & 7;
    const int n0 = (flat >> 3) * 64;

    // This wave's Q fragment (B-operand), loop-invariant: n = n0 + w*16 + l16
    const bf16x8 qfrag = *(const bf16x8*)(qT + ((size_t)b * N_ + n0 + w * 16 + l16) * DQK_ + quad * 8);

    f32x4 acc[16];   // c-tile i: c = i*16 + quad*4 + r, n = n0 + w*16 + l16
#pragma unroll
    for (int i = 0; i < 16; ++i) acc[i] = (f32x4){0.f, 0.f, 0.f, 0.f};
    f32x4 lsum = (f32x4){0.f, 0.f, 0.f, 0.f};   // 4 indep chains, n = l16 of this wave's tile

    const bf16* kbase = kT + (size_t)b * N_ * DQK_;
    const bf16* vbase = vv + (size_t)b * CQ_ * N_ + (size_t)l16 * N_ + quad * 8;

    bf16* const Pw0 = &P[w][0][0][0];
    bf16* const Pw1 = &P[w][1][0][0];

    auto loadK = [&](int mt, bf16x8* dst) {
        for (int im = 0; im < 4; ++im)
            dst[im] = *(const bf16x8*)(kbase + (size_t)(mt * 64 + im * 16 + l16) * DQK_ + quad * 8);
    };
    // S^T for one m-tile (this wave's 16 n-cols): 4 swapped-operand MFMAs,
    // exp, private P write. D: col(l16)=n, row(quad*4+r)=m_local.
    auto computeS = [&](const bf16x8* kfr, bf16* Pb) {
        for (int im = 0; im < 4; ++im) {
            f32x4 s = __builtin_amdgcn_mfma_f32_16x16x32_bf16(kfr[im], qfrag,
                                                              (f32x4){0.f, 0.f, 0.f, 0.f}, 0, 0, 0);
            bf16x4 pk;
            for (int r = 0; r < 4; ++r) {
                float p = __expf(s[r]);
                lsum[r] += p;
                pk[r] = (bf16)p;
            }
            *(bf16x4*)&Pb[l16 * 64 + ((im * 16 + quad * 4) ^ swz)] = pk;
        }
    };

    // prologue: S(0) -> buf0; kf <- K(1)
    bf16x8 kf[4];
    loadK(0, kf);
    computeS(kf, Pw0);
    loadK(1, kf);

    const int roff0 = l16 * 64 + ((quad * 8) ^ swz);        // ks=0 B-frag
    const int roff1 = l16 * 64 + ((32 + quad * 8) ^ swz);   // ks=1 B-frag

    for (int t = 0; t < 63; ++t) {
        bf16* Pr = (t & 1) ? Pw1 : Pw0;     // written at iter t-1 (same wave)
        bf16* Pwr = (t & 1) ? Pw0 : Pw1;    // to be read at iter t+1
        // issue P(t) reads early; in-order DS per wave guarantees data
        bf16x8 pf0 = *(const bf16x8*)&Pr[roff0];
        bf16x8 pf1 = *(const bf16x8*)&Pr[roff1];
        // S(t+1) -> other buffer (independent of pf reads)
        computeS(kf, Pwr);
        bf16x8 kn[4];
        loadK(t + 2 < 64 ? t + 2 : 0, kn);
        // PV(t): O[all 256 c][this wave's 16 n] += V[:, m-tile] P^T
        const bf16* vp = vbase + t * 64;
#pragma unroll
        for (int i = 0; i < 16; ++i) {
            bf16x8 v0 = *(const bf16x8*)(vp + (size_t)i * (16 * N_));
            bf16x8 v1 = *(const bf16x8*)(vp + (size_t)i * (16 * N_) + 32);
            acc[i] = __builtin_amdgcn_mfma_f32_16x16x32_bf16(v0, pf0, acc[i], 0, 0, 0);
            acc[i] = __builtin_amdgcn_mfma_f32_16x16x32_bf16(v1, pf1, acc[i], 0, 0, 0);
        }
        for (int im = 0; im < 4; ++im) kf[im] = kn[im];
    }
    // tail: PV(63) from buf1 (63&1 = 1)
    {
        bf16x8 pf0 = *(const bf16x8*)&Pw1[roff0];
        bf16x8 pf1 = *(const bf16x8*)&Pw1[roff1];
        const bf16* vp = vbase + 63 * 64;
#pragma unroll
        for (int i = 0; i < 16; ++i) {
            bf16x8 v0 = *(const bf16x8*)(vp + (size_t)i * (16 * N_));
            bf16x8 v1 = *(const bf16x8*)(vp + (size_t)i * (16 * N_) + 32);
            acc[i] = __builtin_amdgcn_mfma_f32_16x16x32_bf16(v0, pf0, acc[i], 0, 0, 0);
            acc[i] = __builtin_amdgcn_mfma_f32_16x16x32_bf16(v1, pf1, acc[i], 0, 0, 0);
        }
    }
    // softmax denominator: fully lane-local after quad reduce (lanes l16+16k share n)
    float s = (lsum[0] + lsum[1]) + (lsum[2] + lsum[3]);
    s += __shfl_xor(s, 16);
    s += __shfl_xor(s, 32);
    const float linv = 1.f / s;
    const float g = gamma[0];
    const int n = n0 + w * 16 + l16;
#pragma unroll
    for (int i = 0; i < 16; ++i)
        for (int r = 0; r < 4; ++r) {
            int c = i * 16 + quad * 4 + r;
            size_t idx = ((size_t)b * CQ_ + c) * N_ + n;
            out[idx] = g * acc[i][r] * linv + query[idx];
        }
}

extern "C" void kernel_launch(void* const* d_in, const int* in_sizes, int n_in,
                              void* d_out, int out_size, void* d_ws, size_t ws_size,
                              hipStream_t stream) {
    const float* query     = (const float*)d_in[0];
    const float* key_value = (const float*)d_in[1];
    const float* Wq = (const float*)d_in[2];
    const float* bq = (const float*)d_in[3];
    const float* Wk = (const float*)d_in[4];
    const float* bk = (const float*)d_in[5];
    const float* Wv = (const float*)d_in[6];
    const float* bv = (const float*)d_in[7];
    const float* gamma = (const float*)d_in[8];
    float* out = (float*)d_out;

    char* ws = (char*)d_ws;
    bf16* kvr  = (bf16*)(ws);              // [8][4096][512]  33,554,432 B
    bf16* vbuf = (bf16*)(ws + 33554432);   // [8][256][4096]  16,777,216 B
    bf16* qTb  = (bf16*)(ws + 50331648);   // [8][4096][32]    2,097,152 B
    bf16* kTb  = (bf16*)(ws + 52428800);   // [8][4096][32]    2,097,152 B
    bf16* wqb  = (bf16*)(ws + 54525952);   // [32][256]           16,384 B
    bf16* wkb  = (bf16*)(ws + 54542336);   // [32][512]           32,768 B
    bf16* wvb  = (bf16*)(ws + 54575104);   // [256][512]         262,144 B

    k_convert_w<<<608, 256, 0, stream>>>(Wq, Wk, Wv, wqb, wkb, wvb);
    k_resize<<<dim3(64, 8), 256, 0, stream>>>(key_value, kvr);
    k_proj_q_fused<<<dim3(64, 8), 256, 0, stream>>>(query, wqb, bq, qTb);
    k_proj_k<<<dim3(32, 8), 256, 0, stream>>>(wkb, bk, kvr, kTb);
    k_proj_v<<<dim3(64, 8), 256, 0, stream>>>(wvb, bv, kvr, vbuf);
    k_flash<<<dim3(64, 8), 256, 0, stream>>>(qTb, kTb, vbuf, query, gamma, out);
}

// Round 7
// 600.672 us; speedup vs baseline: 1.1447x; 1.1447x over previous
//
#include <hip/hip_runtime.h>

#define B_ 8
#define CQ_ 256
#define CKV_ 512
#define N_ 4096
#define DQK_ 32
#define LOG2E 1.44269504f

typedef __bf16 bf16;
typedef __bf16 bf16x4 __attribute__((ext_vector_type(4)));
typedef __bf16 bf16x8 __attribute__((ext_vector_type(8)));
typedef float f32x4 __attribute__((ext_vector_type(4)));

// ---------------- weight convert fp32 -> bf16 (Wq pre-scaled by log2e) ----------------
__global__ void k_convert_w(const float* __restrict__ Wq, const float* __restrict__ Wk,
                            const float* __restrict__ Wv,
                            bf16* __restrict__ wq, bf16* __restrict__ wk, bf16* __restrict__ wv) {
    int i = blockIdx.x * 256 + threadIdx.x;
    if (i < 8192) wq[i] = (bf16)(Wq[i] * LOG2E);
    else if (i < 24576) wk[i - 8192] = (bf16)Wk[i - 8192];
    else if (i < 155648) wv[i - 24576] = (bf16)Wv[i - 24576];
}

// ---------------- bilinear resize 32x32 -> 64x64, transposed to [b][n][u] ----------------
// z-split: each block handles one 64-channel chunk (16 blocks/CU -> latency-hidden)
__global__ __launch_bounds__(256) void k_resize(const float* __restrict__ kv, bf16* __restrict__ kvr) {
    const int yo = blockIdx.x;   // output row 0..63
    const int b  = blockIdx.y;
    const int uc = blockIdx.z * 64;
    const int tid = threadIdx.x;
    __shared__ float r0[64][33];
    __shared__ float r1[64][33];
    int ty = yo >> 1;
    int y0, y1; float wy0, wy1;
    if ((yo & 1) == 0) { y0 = ty > 0 ? ty - 1 : 0; y1 = ty; wy0 = 0.25f; wy1 = 0.75f; }
    else               { y0 = ty; y1 = ty < 31 ? ty + 1 : 31; wy0 = 0.75f; wy1 = 0.25f; }
    const int u_loc = tid & 63;
    const int xo_base = tid >> 6;
    for (int i = 0; i < 8; ++i) {
        int idx = tid + i * 256;
        int u = idx >> 5, x = idx & 31;
        const float* src = kv + ((size_t)b * CKV_ + uc + u) * 1024 + x;
        r0[u][x] = src[y0 * 32];
        r1[u][x] = src[y1 * 32];
    }
    __syncthreads();
    for (int i = 0; i < 16; ++i) {
        int xo = xo_base + i * 4;
        int tx = xo >> 1;
        int xa, xb; float wxa, wxb;
        if ((xo & 1) == 0) { xa = tx > 0 ? tx - 1 : 0; xb = tx; wxa = 0.25f; wxb = 0.75f; }
        else               { xa = tx; xb = tx < 31 ? tx + 1 : 31; wxa = 0.75f; wxb = 0.25f; }
        float v0 = wxa * r0[u_loc][xa] + wxb * r0[u_loc][xb];
        float v1 = wxa * r1[u_loc][xa] + wxb * r1[u_loc][xb];
        float val = wy0 * v0 + wy1 * v1;
        kvr[((size_t)b * N_ + yo * 64 + xo) * CKV_ + uc + u_loc] = (bf16)val;
    }
}

// ---------------- fused: transpose query tile to LDS + q projection ----------------
// output qTb scaled by log2e: W carries the scale (convert), bias scaled here.
__global__ __launch_bounds__(256) void k_proj_q_fused(const float* __restrict__ query,
                                                      const bf16* __restrict__ W,     // [32][256] (pre-scaled)
                                                      const float* __restrict__ bias, // [32]
                                                      bf16* __restrict__ qTb) {       // [B][N][32]
    __shared__ bf16 tile[64][264];   // [n][c], row stride 528B (16B-aligned)
    const int n0 = blockIdx.x * 64;
    const int b  = blockIdx.y;
    const int tid = threadIdx.x;
    const int xi = tid & 15, c0 = tid >> 4;
    for (int pass = 0; pass < 16; ++pass) {
        int c = c0 + pass * 16;
        const float4 v = *(const float4*)(query + ((size_t)b * CQ_ + c) * N_ + n0 + xi * 4);
        tile[xi * 4 + 0][c] = (bf16)v.x;
        tile[xi * 4 + 1][c] = (bf16)v.y;
        tile[xi * 4 + 2][c] = (bf16)v.z;
        tile[xi * 4 + 3][c] = (bf16)v.w;
    }
    __syncthreads();
    const int w = tid >> 6, lane = tid & 63;
    const int l16 = lane & 15, quad = lane >> 4;
    const int ct = w & 1, nh = w >> 1;
    f32x4 acc[2];
    acc[0] = (f32x4){0.f, 0.f, 0.f, 0.f}; acc[1] = (f32x4){0.f, 0.f, 0.f, 0.f};
    const bf16* aptr = W + (ct * 16 + l16) * CQ_ + quad * 8;
#pragma unroll
    for (int ks = 0; ks < 8; ++ks) {
        bf16x8 af = *(const bf16x8*)(aptr + ks * 32);
        for (int j = 0; j < 2; ++j) {
            bf16x8 bfv = *(const bf16x8*)&tile[nh * 32 + j * 16 + l16][ks * 32 + quad * 8];
            acc[j] = __builtin_amdgcn_mfma_f32_16x16x32_bf16(af, bfv, acc[j], 0, 0, 0);
        }
    }
    for (int j = 0; j < 2; ++j)
        for (int r = 0; r < 4; ++r) {
            int d = ct * 16 + quad * 4 + r;
            int n = n0 + nh * 32 + j * 16 + l16;
            qTb[((size_t)b * N_ + n) * DQK_ + d] = (bf16)(acc[j][r] + bias[d] * LOG2E);
        }
}

// ---------------- k projection (32-m blocks, 4 blocks/CU) ----------------
__global__ __launch_bounds__(256) void k_proj_k(const bf16* __restrict__ W,     // [32][512]
                                                const float* __restrict__ bias, // [32]
                                                const bf16* __restrict__ Bm,    // [B][N][512]
                                                bf16* __restrict__ outT) {      // [B][N][32]
    const int flat = blockIdx.x + 128 * blockIdx.y;
    const int b  = flat & 7;
    const int mb = (flat >> 3) * 32;
    const int tid = threadIdx.x;
    const int w = tid >> 6, lane = tid & 63;
    const int l16 = lane & 15, quad = lane >> 4;
    const int ct = w & 1;
    const int mh = (w >> 1) * 16;
    f32x4 acc = (f32x4){0.f, 0.f, 0.f, 0.f};
    const bf16* aptr = W + (ct * 16 + l16) * CKV_ + quad * 8;
    const bf16* bptr = Bm + ((size_t)b * N_ + mb + mh + l16) * CKV_ + quad * 8;
#pragma unroll
    for (int ks = 0; ks < 16; ++ks) {
        bf16x8 af  = *(const bf16x8*)(aptr + ks * 32);
        bf16x8 bfv = *(const bf16x8*)(bptr + ks * 32);
        acc = __builtin_amdgcn_mfma_f32_16x16x32_bf16(af, bfv, acc, 0, 0, 0);
    }
    const int m = mb + mh + l16;
    for (int r = 0; r < 4; ++r) {
        int d = ct * 16 + quad * 4 + r;
        outT[((size_t)b * N_ + m) * DQK_ + d] = (bf16)(acc[r] + bias[d]);
    }
}

// ---------------- v projection (32-m blocks, 4 blocks/CU) ----------------
__global__ __launch_bounds__(256) void k_proj_v(const bf16* __restrict__ W,     // [256][512]
                                                const float* __restrict__ bias, // [256]
                                                const bf16* __restrict__ Bm,    // [B][N][512]
                                                bf16* __restrict__ vout) {      // [B][256][N]
    const int flat = blockIdx.x + 128 * blockIdx.y;
    const int b  = flat & 7;
    const int mb = (flat >> 3) * 32;
    const int tid = threadIdx.x;
    const int w = tid >> 6, lane = tid & 63;
    const int l16 = lane & 15, quad = lane >> 4;
    f32x4 acc[4][2];
    for (int i = 0; i < 4; ++i) for (int j = 0; j < 2; ++j) acc[i][j] = (f32x4){0.f, 0.f, 0.f, 0.f};
    const bf16* bbase = Bm + ((size_t)b * N_ + mb) * CKV_ + quad * 8;
#pragma unroll 4
    for (int ks = 0; ks < 16; ++ks) {
        bf16x8 bfv[2];
        for (int j = 0; j < 2; ++j)
            bfv[j] = *(const bf16x8*)(bbase + (size_t)(j * 16 + l16) * CKV_ + ks * 32);
        for (int i = 0; i < 4; ++i) {
            bf16x8 af = *(const bf16x8*)(W + (size_t)((w * 4 + i) * 16 + l16) * CKV_ + ks * 32 + quad * 8);
            for (int j = 0; j < 2; ++j)
                acc[i][j] = __builtin_amdgcn_mfma_f32_16x16x32_bf16(af, bfv[j], acc[i][j], 0, 0, 0);
        }
    }
    for (int i = 0; i < 4; ++i)
        for (int r = 0; r < 4; ++r) {
            int c = (w * 4 + i) * 16 + quad * 4 + r;
            float bvs = bias[c];
            for (int j = 0; j < 2; ++j) {
                int m = mb + j * 16 + l16;
                vout[((size_t)b * CQ_ + c) * N_ + m] = (bf16)(acc[i][j][r] + bvs);
            }
        }
}

// ---------------- flash attention: 8 waves, in-block m-split, 16 waves/CU ----------------
// Round-1 partition (verified) kept exactly: within each m-half group of 4
// waves, wave w computes S for n-slice w and PV for c-slice w*64 through a
// shared double-buffered P. The 64 m-tiles split across two 4-wave groups
// (h = wave>>2 takes tiles 2t+h), halving per-wave loop depth and doubling
// resident waves/CU (2 blocks x 8 waves = 16 waves/CU = 4/SIMD). Partial
// denominators and partial O combined once at the end through LDS. Batch<->XCD
// remap kept (FETCH 91->27 MB). exp is a single v_exp_f32 (exp2f; log2e
// folded into the q projection).
__global__ __launch_bounds__(512, 4) void k_flash(const bf16* __restrict__ qT,   // [B][N][32]
                                                  const bf16* __restrict__ kT,   // [B][N][32]
                                                  const bf16* __restrict__ vv,   // [B][256][N]
                                                  const float* __restrict__ query,
                                                  const float* __restrict__ gamma,
                                                  float* __restrict__ out) {
    __shared__ bf16 P[2][2][64][72];   // [m-half][dbuf][n][m-swz]: 36,864 B
    __shared__ float lpart[2][64];     // partial softmax denom per half
    const int tid = threadIdx.x;
    const int w8 = tid >> 6;           // 0..7
    const int h  = w8 >> 2;            // m-half group
    const int w  = w8 & 3;             // n-slice (S) / c-slice (PV)
    const int lane = tid & 63;
    const int l16 = lane & 15, quad = lane >> 4;
    const int swz = l16 & 3;
    // batch<->XCD remap: blocks with flat%8==b all process batch b
    const int flat = blockIdx.x + 64 * blockIdx.y;
    const int b  = flat & 7;
    const int n0 = (flat >> 3) * 64;

    // Q fragment (B-operand), loop-invariant: n = n0 + w*16 + l16
    const bf16x8 qfrag = *(const bf16x8*)(qT + ((size_t)b * N_ + n0 + w * 16 + l16) * DQK_ + quad * 8);

    f32x4 acc[16];   // [i*4+j]: c = w*64+i*16+quad*4+r, n = n0+j*16+l16 (partial over m-half)
#pragma unroll
    for (int i = 0; i < 16; ++i) acc[i] = (f32x4){0.f, 0.f, 0.f, 0.f};
    f32x4 lsum = (f32x4){0.f, 0.f, 0.f, 0.f};

    const bf16* kbase = kT + (size_t)b * N_ * DQK_;
    const bf16* vbase = vv + ((size_t)b * CQ_ + w * 64) * N_;

    auto loadK = [&](int mt, bf16x8* dst) {
        for (int im = 0; im < 4; ++im)
            dst[im] = *(const bf16x8*)(kbase + (size_t)(mt * 64 + im * 16 + l16) * DQK_ + quad * 8);
    };

    bf16x8 kf[4];
    loadK(h, kf);   // first tile of this half

#pragma unroll 2
    for (int t = 0; t < 32; ++t) {
        const int mt = 2 * t + h;
        const int m0 = mt * 64;
        // V fragments (A-operand): c = w*64 + i*16 + l16, k = m
        bf16x8 vf[2][4];
        for (int ks = 0; ks < 2; ++ks)
            for (int i = 0; i < 4; ++i)
                vf[ks][i] = *(const bf16x8*)(vbase + (size_t)(i * 16 + l16) * N_ + m0 + ks * 32 + quad * 8);
        // prefetch next K tile of this half (dead on last iter)
        bf16x8 kn[4];
        loadK(mt + 2 < 64 ? mt + 2 : 0, kn);
        // S: 4 swapped-operand MFMAs, exp2, P write. D: col(l16)=n, row(quad*4+r)=m_local
        bf16 (* __restrict__ Pb)[72] = P[h][t & 1];
        for (int im = 0; im < 4; ++im) {
            f32x4 s = __builtin_amdgcn_mfma_f32_16x16x32_bf16(kf[im], qfrag,
                                                              (f32x4){0.f, 0.f, 0.f, 0.f}, 0, 0, 0);
            bf16x4 pk;
            for (int r = 0; r < 4; ++r) {
                float p = exp2f(s[r]);
                lsum[r] += p;
                pk[r] = (bf16)p;
            }
            *(bf16x4*)&Pb[w * 16 + l16][((im ^ swz) << 4) + quad * 4] = pk;
        }
        for (int im = 0; im < 4; ++im) kf[im] = kn[im];
        __syncthreads();
        // PV: O += V P^T from this half's fresh buffer
        __builtin_amdgcn_s_setprio(1);
        for (int ks = 0; ks < 2; ++ks) {
            bf16x8 pf[4];
            for (int j = 0; j < 4; ++j)
                pf[j] = *(const bf16x8*)&Pb[j * 16 + l16]
                            [((((ks << 1) | (quad >> 1)) ^ swz) << 4) + ((quad & 1) << 3)];
            for (int i = 0; i < 4; ++i)
                for (int j = 0; j < 4; ++j)
                    acc[i * 4 + j] = __builtin_amdgcn_mfma_f32_16x16x32_bf16(vf[ks][i], pf[j], acc[i * 4 + j], 0, 0, 0);
        }
        __builtin_amdgcn_s_setprio(0);
    }

    // ---- partial denominator: n = w*16+l16, this half ----
    float sden = (lsum[0] + lsum[1]) + (lsum[2] + lsum[3]);
    sden += __shfl_xor(sden, 16);
    sden += __shfl_xor(sden, 32);
    if (lane < 16) lpart[h][w * 16 + l16] = sden;
    __syncthreads();   // lpart visible; all loop DS reads drained (P reusable)

    // ---- cross-half O combine through LDS (h==0 keeps j 0,1; h==1 keeps j 2,3) ----
    float* fb = (float*)&P[0][0][0][0];   // 32 KiB scratch inside P
    for (int pass = 0; pass < 2; ++pass) {
        const int ibase = pass * 2;
        for (int i = 0; i < 2; ++i)
            for (int jj = 0; jj < 2; ++jj) {
                int jg = (h == 0) ? 2 + jj : jj;   // give away
                int slot = ((i * 2 + jj) * 512 + w8 * 64 + lane) * 4;
                *(f32x4*)&fb[slot] = acc[(ibase + i) * 4 + jg];
            }
        __syncthreads();
        for (int i = 0; i < 2; ++i)
            for (int jj = 0; jj < 2; ++jj) {
                int jk = (h == 0) ? jj : 2 + jj;   // keep (partner gave exactly this j)
                int slot = ((i * 2 + jj) * 512 + (w8 ^ 4) * 64 + lane) * 4;
                acc[(ibase + i) * 4 + jk] += *(const f32x4*)&fb[slot];
            }
        __syncthreads();
    }

    float linv[2];
    for (int jj = 0; jj < 2; ++jj) {
        int jk = (h == 0) ? jj : 2 + jj;
        linv[jj] = 1.f / (lpart[0][jk * 16 + l16] + lpart[1][jk * 16 + l16]);
    }
    const float g = gamma[0];
    for (int i = 0; i < 4; ++i)
        for (int r = 0; r < 4; ++r) {
            int c = w * 64 + i * 16 + quad * 4 + r;
            for (int jj = 0; jj < 2; ++jj) {
                int jk = (h == 0) ? jj : 2 + jj;
                int n = n0 + jk * 16 + l16;
                size_t idx = ((size_t)b * CQ_ + c) * N_ + n;
                out[idx] = g * acc[i * 4 + jk][r] * linv[jj] + query[idx];
            }
        }
}

extern "C" void kernel_launch(void* const* d_in, const int* in_sizes, int n_in,
                              void* d_out, int out_size, void* d_ws, size_t ws_size,
                              hipStream_t stream) {
    const float* query     = (const float*)d_in[0];
    const float* key_value = (const float*)d_in[1];
    const float* Wq = (const float*)d_in[2];
    const float* bq = (const float*)d_in[3];
    const float* Wk = (const float*)d_in[4];
    const float* bk = (const float*)d_in[5];
    const float* Wv = (const float*)d_in[6];
    const float* bv = (const float*)d_in[7];
    const float* gamma = (const float*)d_in[8];
    float* out = (float*)d_out;

    char* ws = (char*)d_ws;
    bf16* kvr  = (bf16*)(ws);              // [8][4096][512]  33,554,432 B
    bf16* vbuf = (bf16*)(ws + 33554432);   // [8][256][4096]  16,777,216 B
    bf16* qTb  = (bf16*)(ws + 50331648);   // [8][4096][32]    2,097,152 B
    bf16* kTb  = (bf16*)(ws + 52428800);   // [8][4096][32]    2,097,152 B
    bf16* wqb  = (bf16*)(ws + 54525952);   // [32][256]           16,384 B
    bf16* wkb  = (bf16*)(ws + 54542336);   // [32][512]           32,768 B
    bf16* wvb  = (bf16*)(ws + 54575104);   // [256][512]         262,144 B

    k_convert_w<<<608, 256, 0, stream>>>(Wq, Wk, Wv, wqb, wkb, wvb);
    k_resize<<<dim3(64, 8, 8), 256, 0, stream>>>(key_value, kvr);
    k_proj_q_fused<<<dim3(64, 8), 256, 0, stream>>>(query, wqb, bq, qTb);
    k_proj_k<<<dim3(128, 8), 256, 0, stream>>>(wkb, bk, kvr, kTb);
    k_proj_v<<<dim3(128, 8), 256, 0, stream>>>(wvb, bv, kvr, vbuf);
    k_flash<<<dim3(64, 8), 512, 0, stream>>>(qTb, kTb, vbuf, query, gamma, out);
}

// Round 8
// 360.410 us; speedup vs baseline: 1.9078x; 1.6666x over previous
//
#include <hip/hip_runtime.h>

#define B_ 8
#define CQ_ 256
#define CKV_ 512
#define N_ 4096
#define DQK_ 32
#define LOG2E 1.44269504f

typedef __bf16 bf16;
typedef __bf16 bf16x4 __attribute__((ext_vector_type(4)));
typedef __bf16 bf16x8 __attribute__((ext_vector_type(8)));
typedef float f32x4 __attribute__((ext_vector_type(4)));

// ---------------- weight convert fp32 -> bf16 (Wq pre-scaled by log2e) ----------------
__global__ void k_convert_w(const float* __restrict__ Wq, const float* __restrict__ Wk,
                            const float* __restrict__ Wv,
                            bf16* __restrict__ wq, bf16* __restrict__ wk, bf16* __restrict__ wv) {
    int i = blockIdx.x * 256 + threadIdx.x;
    if (i < 8192) wq[i] = (bf16)(Wq[i] * LOG2E);
    else if (i < 24576) wk[i - 8192] = (bf16)Wk[i - 8192];
    else if (i < 155648) wv[i - 24576] = (bf16)Wv[i - 24576];
}

// ---------------- bilinear resize 32x32 -> 64x64, transposed to [b][n][u] ----------------
__global__ __launch_bounds__(256) void k_resize(const float* __restrict__ kv, bf16* __restrict__ kvr) {
    const int yo = blockIdx.x;   // output row 0..63
    const int b  = blockIdx.y;
    const int uc = blockIdx.z * 64;
    const int tid = threadIdx.x;
    __shared__ float r0[64][33];
    __shared__ float r1[64][33];
    int ty = yo >> 1;
    int y0, y1; float wy0, wy1;
    if ((yo & 1) == 0) { y0 = ty > 0 ? ty - 1 : 0; y1 = ty; wy0 = 0.25f; wy1 = 0.75f; }
    else               { y0 = ty; y1 = ty < 31 ? ty + 1 : 31; wy0 = 0.75f; wy1 = 0.25f; }
    const int u_loc = tid & 63;
    const int xo_base = tid >> 6;
    for (int i = 0; i < 8; ++i) {
        int idx = tid + i * 256;
        int u = idx >> 5, x = idx & 31;
        const float* src = kv + ((size_t)b * CKV_ + uc + u) * 1024 + x;
        r0[u][x] = src[y0 * 32];
        r1[u][x] = src[y1 * 32];
    }
    __syncthreads();
    for (int i = 0; i < 16; ++i) {
        int xo = xo_base + i * 4;
        int tx = xo >> 1;
        int xa, xb; float wxa, wxb;
        if ((xo & 1) == 0) { xa = tx > 0 ? tx - 1 : 0; xb = tx; wxa = 0.25f; wxb = 0.75f; }
        else               { xa = tx; xb = tx < 31 ? tx + 1 : 31; wxa = 0.75f; wxb = 0.25f; }
        float v0 = wxa * r0[u_loc][xa] + wxb * r0[u_loc][xb];
        float v1 = wxa * r1[u_loc][xa] + wxb * r1[u_loc][xb];
        float val = wy0 * v0 + wy1 * v1;
        kvr[((size_t)b * N_ + yo * 64 + xo) * CKV_ + uc + u_loc] = (bf16)val;
    }
}

// ---------------- fused: transpose query tile to LDS + q projection ----------------
__global__ __launch_bounds__(256) void k_proj_q_fused(const float* __restrict__ query,
                                                      const bf16* __restrict__ W,     // [32][256] (pre-scaled)
                                                      const float* __restrict__ bias, // [32]
                                                      bf16* __restrict__ qTb) {       // [B][N][32]
    __shared__ bf16 tile[64][264];
    const int n0 = blockIdx.x * 64;
    const int b  = blockIdx.y;
    const int tid = threadIdx.x;
    const int xi = tid & 15, c0 = tid >> 4;
    for (int pass = 0; pass < 16; ++pass) {
        int c = c0 + pass * 16;
        const float4 v = *(const float4*)(query + ((size_t)b * CQ_ + c) * N_ + n0 + xi * 4);
        tile[xi * 4 + 0][c] = (bf16)v.x;
        tile[xi * 4 + 1][c] = (bf16)v.y;
        tile[xi * 4 + 2][c] = (bf16)v.z;
        tile[xi * 4 + 3][c] = (bf16)v.w;
    }
    __syncthreads();
    const int w = tid >> 6, lane = tid & 63;
    const int l16 = lane & 15, quad = lane >> 4;
    const int ct = w & 1, nh = w >> 1;
    f32x4 acc[2];
    acc[0] = (f32x4){0.f, 0.f, 0.f, 0.f}; acc[1] = (f32x4){0.f, 0.f, 0.f, 0.f};
    const bf16* aptr = W + (ct * 16 + l16) * CQ_ + quad * 8;
#pragma unroll
    for (int ks = 0; ks < 8; ++ks) {
        bf16x8 af = *(const bf16x8*)(aptr + ks * 32);
        for (int j = 0; j < 2; ++j) {
            bf16x8 bfv = *(const bf16x8*)&tile[nh * 32 + j * 16 + l16][ks * 32 + quad * 8];
            acc[j] = __builtin_amdgcn_mfma_f32_16x16x32_bf16(af, bfv, acc[j], 0, 0, 0);
        }
    }
    for (int j = 0; j < 2; ++j)
        for (int r = 0; r < 4; ++r) {
            int d = ct * 16 + quad * 4 + r;
            int n = n0 + nh * 32 + j * 16 + l16;
            qTb[((size_t)b * N_ + n) * DQK_ + d] = (bf16)(acc[j][r] + bias[d] * LOG2E);
        }
}

// ---------------- k projection (32-m blocks) ----------------
__global__ __launch_bounds__(256) void k_proj_k(const bf16* __restrict__ W,
                                                const float* __restrict__ bias,
                                                const bf16* __restrict__ Bm,
                                                bf16* __restrict__ outT) {
    const int flat = blockIdx.x + 128 * blockIdx.y;
    const int b  = flat & 7;
    const int mb = (flat >> 3) * 32;
    const int tid = threadIdx.x;
    const int w = tid >> 6, lane = tid & 63;
    const int l16 = lane & 15, quad = lane >> 4;
    const int ct = w & 1;
    const int mh = (w >> 1) * 16;
    f32x4 acc = (f32x4){0.f, 0.f, 0.f, 0.f};
    const bf16* aptr = W + (ct * 16 + l16) * CKV_ + quad * 8;
    const bf16* bptr = Bm + ((size_t)b * N_ + mb + mh + l16) * CKV_ + quad * 8;
#pragma unroll
    for (int ks = 0; ks < 16; ++ks) {
        bf16x8 af  = *(const bf16x8*)(aptr + ks * 32);
        bf16x8 bfv = *(const bf16x8*)(bptr + ks * 32);
        acc = __builtin_amdgcn_mfma_f32_16x16x32_bf16(af, bfv, acc, 0, 0, 0);
    }
    const int m = mb + mh + l16;
    for (int r = 0; r < 4; ++r) {
        int d = ct * 16 + quad * 4 + r;
        outT[((size_t)b * N_ + m) * DQK_ + d] = (bf16)(acc[r] + bias[d]);
    }
}

// ---------------- v projection (32-m blocks) ----------------
__global__ __launch_bounds__(256) void k_proj_v(const bf16* __restrict__ W,
                                                const float* __restrict__ bias,
                                                const bf16* __restrict__ Bm,
                                                bf16* __restrict__ vout) {
    const int flat = blockIdx.x + 128 * blockIdx.y;
    const int b  = flat & 7;
    const int mb = (flat >> 3) * 32;
    const int tid = threadIdx.x;
    const int w = tid >> 6, lane = tid & 63;
    const int l16 = lane & 15, quad = lane >> 4;
    f32x4 acc[4][2];
    for (int i = 0; i < 4; ++i) for (int j = 0; j < 2; ++j) acc[i][j] = (f32x4){0.f, 0.f, 0.f, 0.f};
    const bf16* bbase = Bm + ((size_t)b * N_ + mb) * CKV_ + quad * 8;
#pragma unroll 4
    for (int ks = 0; ks < 16; ++ks) {
        bf16x8 bfv[2];
        for (int j = 0; j < 2; ++j)
            bfv[j] = *(const bf16x8*)(bbase + (size_t)(j * 16 + l16) * CKV_ + ks * 32);
        for (int i = 0; i < 4; ++i) {
            bf16x8 af = *(const bf16x8*)(W + (size_t)((w * 4 + i) * 16 + l16) * CKV_ + ks * 32 + quad * 8);
            for (int j = 0; j < 2; ++j)
                acc[i][j] = __builtin_amdgcn_mfma_f32_16x16x32_bf16(af, bfv[j], acc[i][j], 0, 0, 0);
        }
    }
    for (int i = 0; i < 4; ++i)
        for (int r = 0; r < 4; ++r) {
            int c = (w * 4 + i) * 16 + quad * 4 + r;
            float bvs = bias[c];
            for (int j = 0; j < 2; ++j) {
                int m = mb + j * 16 + l16;
                vout[((size_t)b * CQ_ + c) * N_ + m] = (bf16)(acc[i][j][r] + bvs);
            }
        }
}

// ---------------- flash attention: round-1 verified body, m-split ACROSS BLOCKS ----------------
// Round-7 lesson: in-block m-split needed 190 live VGPRs under a 128 cap ->
// total spill (WRITE_SIZE 1.19GB). This version keeps the verified round-1/2
// 4-wave structure byte-identical (VGPR 112, LDS 18.4KB) and doubles occupancy
// by GRID instead: blockIdx.z in {0,1} takes interleaved m-tiles 2u+z, grid
// 1024 blocks -> 4 blocks/CU = 16 waves/CU = 4 waves/SIMD (112<=128 regs,
// 4x18.4KB<=160KB LDS both fit). Each block writes UN-normalized partial O
// (f32) and a partial softmax denominator; a memory-bound combine kernel
// finishes (g*(O0+O1)/(l0+l1) + query). Partial buffers reuse `out` (z=0) and
// the dead kvr workspace (z=1) -> only +256KB workspace for denominators.
__global__ __launch_bounds__(256) void k_flash(const bf16* __restrict__ qT,   // [B][N][32]
                                               const bf16* __restrict__ kT,   // [B][N][32]
                                               const bf16* __restrict__ vv,   // [B][256][N]
                                               float* __restrict__ o0,        // [B][256][N] partial z=0
                                               float* __restrict__ o1,        // [B][256][N] partial z=1
                                               float* __restrict__ ls0,       // [B][N]
                                               float* __restrict__ ls1) {     // [B][N]
    __shared__ bf16 P[2][64][72];   // shared, double-buffered: 18,432 B
    const int z = blockIdx.z;
    const int tid = threadIdx.x;
    const int w = tid >> 6, lane = tid & 63;
    const int l16 = lane & 15, quad = lane >> 4;
    const int swz = l16 & 3;
    // batch<->XCD remap: blocks with flat%8==b all process batch b
    const int flat = blockIdx.x + 64 * blockIdx.y;
    const int b  = flat & 7;
    const int n0 = (flat >> 3) * 64;

    // Q fragment (B-operand), loop-invariant: n = n0 + w*16 + l16
    const bf16x8 qfrag = *(const bf16x8*)(qT + ((size_t)b * N_ + n0 + w * 16 + l16) * DQK_ + quad * 8);

    f32x4 acc[4][4];   // [c-tile i][n-tile j]: c = w*64+i*16+quad*4+r, n = n0+j*16+l16
    for (int i = 0; i < 4; ++i) for (int j = 0; j < 4; ++j) acc[i][j] = (f32x4){0.f, 0.f, 0.f, 0.f};
    f32x4 lsum = (f32x4){0.f, 0.f, 0.f, 0.f};

    const bf16* kbase = kT + (size_t)b * N_ * DQK_;
    const bf16* vbase = vv + ((size_t)b * CQ_ + w * 64) * N_;

    auto loadK = [&](int mt, bf16x8* dst) {
        for (int im = 0; im < 4; ++im)
            dst[im] = *(const bf16x8*)(kbase + (size_t)(mt * 64 + im * 16 + l16) * DQK_ + quad * 8);
    };
    // S^T for one m-tile (this wave's 16 n-cols): 4 swapped-operand MFMAs,
    // exp2 (log2e pre-folded), shared P write. D: col(l16)=n, row(quad*4+r)=m_local.
    auto computeS = [&](const bf16x8* kfr, bf16 (*Pb)[72]) {
        for (int im = 0; im < 4; ++im) {
            f32x4 s = __builtin_amdgcn_mfma_f32_16x16x32_bf16(kfr[im], qfrag,
                                                              (f32x4){0.f, 0.f, 0.f, 0.f}, 0, 0, 0);
            bf16x4 pk;
            for (int r = 0; r < 4; ++r) {
                float p = exp2f(s[r]);
                lsum[r] += p;
                pk[r] = (bf16)p;
            }
            *(bf16x4*)&Pb[w * 16 + l16][((im ^ swz) << 4) + quad * 4] = pk;
        }
    };
    // this block's tile sequence: mt(u) = 2u + z, u = 0..31
    // prologue: S(u=0) -> P[0]; kf <- K(u=1)
    bf16x8 kf[4];
    loadK(z, kf);
    computeS(kf, P[0]);
    loadK(2 + z, kf);
    __syncthreads();

    for (int u = 0; u < 31; ++u) {
        const int m0 = (2 * u + z) * 64;
        // V(u) fragments (A-operand): c = w*64 + i*16 + l16, k = m
        bf16x8 vf[2][4];
        for (int ks = 0; ks < 2; ++ks)
            for (int i = 0; i < 4; ++i)
                vf[ks][i] = *(const bf16x8*)(vbase + (size_t)(i * 16 + l16) * N_ + m0 + ks * 32 + quad * 8);
        // prefetch K(u+2) (dead wrap on last iters)
        bf16x8 kn[4];
        loadK(u + 2 < 32 ? 2 * (u + 2) + z : z, kn);
        // S(u+1) -> P[(u+1)&1]  (interleaves with PV(u) below)
        computeS(kf, P[(u + 1) & 1]);
        // PV(u): O += V P^T from P[u&1]
        bf16 (* __restrict__ Pb)[72] = P[u & 1];
        __builtin_amdgcn_s_setprio(1);
        for (int ks = 0; ks < 2; ++ks) {
            bf16x8 pf[4];
            for (int j = 0; j < 4; ++j)
                pf[j] = *(const bf16x8*)&Pb[j * 16 + l16]
                            [((((ks << 1) | (quad >> 1)) ^ swz) << 4) + ((quad & 1) << 3)];
            for (int i = 0; i < 4; ++i)
                for (int j = 0; j < 4; ++j)
                    acc[i][j] = __builtin_amdgcn_mfma_f32_16x16x32_bf16(vf[ks][i], pf[j], acc[i][j], 0, 0, 0);
        }
        __builtin_amdgcn_s_setprio(0);
        for (int im = 0; im < 4; ++im) kf[im] = kn[im];
        __syncthreads();
    }
    // peeled tail: PV(u=31) from P[1]
    {
        const int m0 = (62 + z) * 64;
        bf16x8 vf[2][4];
        for (int ks = 0; ks < 2; ++ks)
            for (int i = 0; i < 4; ++i)
                vf[ks][i] = *(const bf16x8*)(vbase + (size_t)(i * 16 + l16) * N_ + m0 + ks * 32 + quad * 8);
        bf16 (* __restrict__ Pb)[72] = P[1];
        for (int ks = 0; ks < 2; ++ks) {
            bf16x8 pf[4];
            for (int j = 0; j < 4; ++j)
                pf[j] = *(const bf16x8*)&Pb[j * 16 + l16]
                            [((((ks << 1) | (quad >> 1)) ^ swz) << 4) + ((quad & 1) << 3)];
            for (int i = 0; i < 4; ++i)
                for (int j = 0; j < 4; ++j)
                    acc[i][j] = __builtin_amdgcn_mfma_f32_16x16x32_bf16(vf[ks][i], pf[j], acc[i][j], 0, 0, 0);
        }
    }
    // partial denominator for this wave's n-col (quads share n via shfl)
    float s = (lsum[0] + lsum[1]) + (lsum[2] + lsum[3]);
    s += __shfl_xor(s, 16);
    s += __shfl_xor(s, 32);
    float* lsz = z ? ls1 : ls0;
    if (quad == 0) lsz[(size_t)b * N_ + n0 + w * 16 + l16] = s;
    // partial O store (un-normalized, f32)
    float* oz = z ? o1 : o0;
    for (int i = 0; i < 4; ++i)
        for (int r = 0; r < 4; ++r) {
            int c = w * 64 + i * 16 + quad * 4 + r;
            for (int j = 0; j < 4; ++j) {
                int n = n0 + j * 16 + l16;
                oz[((size_t)b * CQ_ + c) * N_ + n] = acc[i][j][r];
            }
        }
}

// ---------------- combine: out = g*(O0+O1)/(l0+l1) + query ----------------
__global__ __launch_bounds__(256) void k_combine(const float* __restrict__ o1,
                                                 const float* __restrict__ ls0,
                                                 const float* __restrict__ ls1,
                                                 const float* __restrict__ query,
                                                 const float* __restrict__ gamma,
                                                 float* __restrict__ out) {   // also holds O0
    const float g = gamma[0];
    const size_t total = (size_t)B_ * CQ_ * (N_ / 4);   // 2,097,152 float4
    for (size_t i = (size_t)blockIdx.x * 256 + threadIdx.x; i < total; i += (size_t)gridDim.x * 256) {
        size_t n4 = i & (N_ / 4 - 1);
        size_t b  = i >> 18;              // / (256 c * 1024 n4)
        float4 a0 = ((const float4*)out)[i];
        float4 a1 = ((const float4*)o1)[i];
        float4 l0 = *(const float4*)&ls0[b * N_ + n4 * 4];
        float4 l1 = *(const float4*)&ls1[b * N_ + n4 * 4];
        float4 q  = ((const float4*)query)[i];
        float4 r;
        r.x = g * (a0.x + a1.x) / (l0.x + l1.x) + q.x;
        r.y = g * (a0.y + a1.y) / (l0.y + l1.y) + q.y;
        r.z = g * (a0.z + a1.z) / (l0.z + l1.z) + q.z;
        r.w = g * (a0.w + a1.w) / (l0.w + l1.w) + q.w;
        ((float4*)out)[i] = r;
    }
}

extern "C" void kernel_launch(void* const* d_in, const int* in_sizes, int n_in,
                              void* d_out, int out_size, void* d_ws, size_t ws_size,
                              hipStream_t stream) {
    const float* query     = (const float*)d_in[0];
    const float* key_value = (const float*)d_in[1];
    const float* Wq = (const float*)d_in[2];
    const float* bq = (const float*)d_in[3];
    const float* Wk = (const float*)d_in[4];
    const float* bk = (const float*)d_in[5];
    const float* Wv = (const float*)d_in[6];
    const float* bv = (const float*)d_in[7];
    const float* gamma = (const float*)d_in[8];
    float* out = (float*)d_out;

    char* ws = (char*)d_ws;
    bf16* kvr  = (bf16*)(ws);              // [8][4096][512]  33,554,432 B ; reused as O1 (f32) by k_flash
    bf16* vbuf = (bf16*)(ws + 33554432);   // [8][256][4096]  16,777,216 B
    bf16* qTb  = (bf16*)(ws + 50331648);   // [8][4096][32]    2,097,152 B
    bf16* kTb  = (bf16*)(ws + 52428800);   // [8][4096][32]    2,097,152 B
    bf16* wqb  = (bf16*)(ws + 54525952);   // [32][256]           16,384 B
    bf16* wkb  = (bf16*)(ws + 54542336);   // [32][512]           32,768 B
    bf16* wvb  = (bf16*)(ws + 54575104);   // [256][512]         262,144 B
    float* ls0 = (float*)(ws + 54837248);  // [8][4096]          131,072 B
    float* ls1 = (float*)(ws + 54968320);  // [8][4096]          131,072 B

    k_convert_w<<<608, 256, 0, stream>>>(Wq, Wk, Wv, wqb, wkb, wvb);
    k_resize<<<dim3(64, 8, 8), 256, 0, stream>>>(key_value, kvr);
    k_proj_q_fused<<<dim3(64, 8), 256, 0, stream>>>(query, wqb, bq, qTb);
    k_proj_k<<<dim3(128, 8), 256, 0, stream>>>(wkb, bk, kvr, kTb);
    k_proj_v<<<dim3(128, 8), 256, 0, stream>>>(wvb, bv, kvr, vbuf);
    // kvr dead from here -> reuse as O1 partial (f32, exact 33.5MB fit)
    k_flash<<<dim3(64, 8, 2), 256, 0, stream>>>(qTb, kTb, vbuf, out, (float*)kvr, ls0, ls1);
    k_combine<<<2048, 256, 0, stream>>>((float*)kvr, ls0, ls1, query, gamma, out);
}

// Round 9
// 358.648 us; speedup vs baseline: 1.9171x; 1.0049x over previous
//
#include <hip/hip_runtime.h>

#define B_ 8
#define CQ_ 256
#define CKV_ 512
#define N_ 4096
#define DQK_ 32
#define LOG2E 1.44269504f

typedef __bf16 bf16;
typedef __bf16 bf16x4 __attribute__((ext_vector_type(4)));
typedef __bf16 bf16x8 __attribute__((ext_vector_type(8)));
typedef float f32x4 __attribute__((ext_vector_type(4)));

// ---------------- weight convert fp32 -> bf16 (Wq pre-scaled by log2e) ----------------
__global__ void k_convert_w(const float* __restrict__ Wq, const float* __restrict__ Wk,
                            const float* __restrict__ Wv,
                            bf16* __restrict__ wq, bf16* __restrict__ wk, bf16* __restrict__ wv) {
    int i = blockIdx.x * 256 + threadIdx.x;
    if (i < 8192) wq[i] = (bf16)(Wq[i] * LOG2E);
    else if (i < 24576) wk[i - 8192] = (bf16)Wk[i - 8192];
    else if (i < 155648) wv[i - 24576] = (bf16)Wv[i - 24576];
}

// ---------------- bilinear resize 32x32 -> 64x64, transposed to [b][n][u] ----------------
__global__ __launch_bounds__(256) void k_resize(const float* __restrict__ kv, bf16* __restrict__ kvr) {
    const int yo = blockIdx.x;   // output row 0..63
    const int b  = blockIdx.y;
    const int uc = blockIdx.z * 64;
    const int tid = threadIdx.x;
    __shared__ float r0[64][33];
    __shared__ float r1[64][33];
    int ty = yo >> 1;
    int y0, y1; float wy0, wy1;
    if ((yo & 1) == 0) { y0 = ty > 0 ? ty - 1 : 0; y1 = ty; wy0 = 0.25f; wy1 = 0.75f; }
    else               { y0 = ty; y1 = ty < 31 ? ty + 1 : 31; wy0 = 0.75f; wy1 = 0.25f; }
    const int u_loc = tid & 63;
    const int xo_base = tid >> 6;
    for (int i = 0; i < 8; ++i) {
        int idx = tid + i * 256;
        int u = idx >> 5, x = idx & 31;
        const float* src = kv + ((size_t)b * CKV_ + uc + u) * 1024 + x;
        r0[u][x] = src[y0 * 32];
        r1[u][x] = src[y1 * 32];
    }
    __syncthreads();
    for (int i = 0; i < 16; ++i) {
        int xo = xo_base + i * 4;
        int tx = xo >> 1;
        int xa, xb; float wxa, wxb;
        if ((xo & 1) == 0) { xa = tx > 0 ? tx - 1 : 0; xb = tx; wxa = 0.25f; wxb = 0.75f; }
        else               { xa = tx; xb = tx < 31 ? tx + 1 : 31; wxa = 0.75f; wxb = 0.25f; }
        float v0 = wxa * r0[u_loc][xa] + wxb * r0[u_loc][xb];
        float v1 = wxa * r1[u_loc][xa] + wxb * r1[u_loc][xb];
        float val = wy0 * v0 + wy1 * v1;
        kvr[((size_t)b * N_ + yo * 64 + xo) * CKV_ + uc + u_loc] = (bf16)val;
    }
}

// ---------------- fused: transpose query tile to LDS + q projection ----------------
__global__ __launch_bounds__(256) void k_proj_q_fused(const float* __restrict__ query,
                                                      const bf16* __restrict__ W,     // [32][256] (pre-scaled)
                                                      const float* __restrict__ bias, // [32]
                                                      bf16* __restrict__ qTb) {       // [B][N][32]
    __shared__ bf16 tile[64][264];
    const int n0 = blockIdx.x * 64;
    const int b  = blockIdx.y;
    const int tid = threadIdx.x;
    const int xi = tid & 15, c0 = tid >> 4;
    for (int pass = 0; pass < 16; ++pass) {
        int c = c0 + pass * 16;
        const float4 v = *(const float4*)(query + ((size_t)b * CQ_ + c) * N_ + n0 + xi * 4);
        tile[xi * 4 + 0][c] = (bf16)v.x;
        tile[xi * 4 + 1][c] = (bf16)v.y;
        tile[xi * 4 + 2][c] = (bf16)v.z;
        tile[xi * 4 + 3][c] = (bf16)v.w;
    }
    __syncthreads();
    const int w = tid >> 6, lane = tid & 63;
    const int l16 = lane & 15, quad = lane >> 4;
    const int ct = w & 1, nh = w >> 1;
    f32x4 acc[2];
    acc[0] = (f32x4){0.f, 0.f, 0.f, 0.f}; acc[1] = (f32x4){0.f, 0.f, 0.f, 0.f};
    const bf16* aptr = W + (ct * 16 + l16) * CQ_ + quad * 8;
#pragma unroll
    for (int ks = 0; ks < 8; ++ks) {
        bf16x8 af = *(const bf16x8*)(aptr + ks * 32);
        for (int j = 0; j < 2; ++j) {
            bf16x8 bfv = *(const bf16x8*)&tile[nh * 32 + j * 16 + l16][ks * 32 + quad * 8];
            acc[j] = __builtin_amdgcn_mfma_f32_16x16x32_bf16(af, bfv, acc[j], 0, 0, 0);
        }
    }
    for (int j = 0; j < 2; ++j)
        for (int r = 0; r < 4; ++r) {
            int d = ct * 16 + quad * 4 + r;
            int n = n0 + nh * 32 + j * 16 + l16;
            qTb[((size_t)b * N_ + n) * DQK_ + d] = (bf16)(acc[j][r] + bias[d] * LOG2E);
        }
}

// ---------------- k projection (32-m blocks) ----------------
__global__ __launch_bounds__(256) void k_proj_k(const bf16* __restrict__ W,
                                                const float* __restrict__ bias,
                                                const bf16* __restrict__ Bm,
                                                bf16* __restrict__ outT) {
    const int flat = blockIdx.x + 128 * blockIdx.y;
    const int b  = flat & 7;
    const int mb = (flat >> 3) * 32;
    const int tid = threadIdx.x;
    const int w = tid >> 6, lane = tid & 63;
    const int l16 = lane & 15, quad = lane >> 4;
    const int ct = w & 1;
    const int mh = (w >> 1) * 16;
    f32x4 acc = (f32x4){0.f, 0.f, 0.f, 0.f};
    const bf16* aptr = W + (ct * 16 + l16) * CKV_ + quad * 8;
    const bf16* bptr = Bm + ((size_t)b * N_ + mb + mh + l16) * CKV_ + quad * 8;
#pragma unroll
    for (int ks = 0; ks < 16; ++ks) {
        bf16x8 af  = *(const bf16x8*)(aptr + ks * 32);
        bf16x8 bfv = *(const bf16x8*)(bptr + ks * 32);
        acc = __builtin_amdgcn_mfma_f32_16x16x32_bf16(af, bfv, acc, 0, 0, 0);
    }
    const int m = mb + mh + l16;
    for (int r = 0; r < 4; ++r) {
        int d = ct * 16 + quad * 4 + r;
        outT[((size_t)b * N_ + m) * DQK_ + d] = (bf16)(acc[r] + bias[d]);
    }
}

// ---------------- v projection (32-m blocks) ----------------
__global__ __launch_bounds__(256) void k_proj_v(const bf16* __restrict__ W,
                                                const float* __restrict__ bias,
                                                const bf16* __restrict__ Bm,
                                                bf16* __restrict__ vout) {
    const int flat = blockIdx.x + 128 * blockIdx.y;
    const int b  = flat & 7;
    const int mb = (flat >> 3) * 32;
    const int tid = threadIdx.x;
    const int w = tid >> 6, lane = tid & 63;
    const int l16 = lane & 15, quad = lane >> 4;
    f32x4 acc[4][2];
    for (int i = 0; i < 4; ++i) for (int j = 0; j < 2; ++j) acc[i][j] = (f32x4){0.f, 0.f, 0.f, 0.f};
    const bf16* bbase = Bm + ((size_t)b * N_ + mb) * CKV_ + quad * 8;
#pragma unroll 4
    for (int ks = 0; ks < 16; ++ks) {
        bf16x8 bfv[2];
        for (int j = 0; j < 2; ++j)
            bfv[j] = *(const bf16x8*)(bbase + (size_t)(j * 16 + l16) * CKV_ + ks * 32);
        for (int i = 0; i < 4; ++i) {
            bf16x8 af = *(const bf16x8*)(W + (size_t)((w * 4 + i) * 16 + l16) * CKV_ + ks * 32 + quad * 8);
            for (int j = 0; j < 2; ++j)
                acc[i][j] = __builtin_amdgcn_mfma_f32_16x16x32_bf16(af, bfv[j], acc[i][j], 0, 0, 0);
        }
    }
    for (int i = 0; i < 4; ++i)
        for (int r = 0; r < 4; ++r) {
            int c = (w * 4 + i) * 16 + quad * 4 + r;
            float bvs = bias[c];
            for (int j = 0; j < 2; ++j) {
                int m = mb + j * 16 + l16;
                vout[((size_t)b * CQ_ + c) * N_ + m] = (bf16)(acc[i][j][r] + bvs);
            }
        }
}

// ---------------- flash attention: c-split across blocks, <=128 unified regs ----------------
// Round-8 finding: unified VGPR+AGPR totals in (128,256] pin residency at
// 2 waves/SIMD (HW quantum; m69), so every prior variant ran at the same
// occupancy regardless of grid. This version splits the CHANNEL dim across
// blockIdx.z (each block: PV over 128 channels, 2 c-tiles/wave) -> acc 32
// regs, vf 16, no kn prefetch (K(u+2) loaded into kf right after computeS
// consumes it; MFMA reads operands at issue, WAR-safe). Peak live ~100,
// capped at 128 via __launch_bounds__(256,4) -> 4 waves/SIMD, 4 blocks/CU.
// S is recomputed in both z-halves (exp x2, was ~15% of cycles) which makes
// the softmax denominator complete in-block: final output written directly,
// no partial buffers, no combine kernel. Q/K/S code is the verified round-1
// structure unchanged; batch<->XCD remap kept (z-halves share an XCD).
__global__ __launch_bounds__(256, 4) void k_flash(const bf16* __restrict__ qT,   // [B][N][32]
                                                  const bf16* __restrict__ kT,   // [B][N][32]
                                                  const bf16* __restrict__ vv,   // [B][256][N]
                                                  const float* __restrict__ query,
                                                  const float* __restrict__ gamma,
                                                  float* __restrict__ out) {
    __shared__ bf16 P[2][64][72];   // shared, double-buffered: 18,432 B
    __shared__ float linvs[64];
    const int z = blockIdx.z;       // channel half: c in [z*128, z*128+128)
    const int tid = threadIdx.x;
    const int w = tid >> 6, lane = tid & 63;
    const int l16 = lane & 15, quad = lane >> 4;
    const int swz = l16 & 3;
    // batch<->XCD remap: blocks with flat%8==b all process batch b
    const int flat = blockIdx.x + 64 * blockIdx.y;
    const int b  = flat & 7;
    const int n0 = (flat >> 3) * 64;

    // Q fragment (B-operand), loop-invariant: n = n0 + w*16 + l16
    const bf16x8 qfrag = *(const bf16x8*)(qT + ((size_t)b * N_ + n0 + w * 16 + l16) * DQK_ + quad * 8);

    f32x4 acc[2][4];   // [c-tile i][n-tile j]: c = z*128+w*32+i*16+quad*4+r, n = n0+j*16+l16
    for (int i = 0; i < 2; ++i) for (int j = 0; j < 4; ++j) acc[i][j] = (f32x4){0.f, 0.f, 0.f, 0.f};
    f32x4 lsum = (f32x4){0.f, 0.f, 0.f, 0.f};

    const bf16* kbase = kT + (size_t)b * N_ * DQK_;
    const bf16* vbase = vv + ((size_t)b * CQ_ + z * 128 + w * 32) * N_;

    auto loadK = [&](int mt, bf16x8* dst) {
        for (int im = 0; im < 4; ++im)
            dst[im] = *(const bf16x8*)(kbase + (size_t)(mt * 64 + im * 16 + l16) * DQK_ + quad * 8);
    };
    // S^T for one m-tile (this wave's 16 n-cols): 4 swapped-operand MFMAs,
    // exp2 (log2e pre-folded), shared P write. D: col(l16)=n, row(quad*4+r)=m_local.
    auto computeS = [&](const bf16x8* kfr, bf16 (*Pb)[72]) {
        for (int im = 0; im < 4; ++im) {
            f32x4 s = __builtin_amdgcn_mfma_f32_16x16x32_bf16(kfr[im], qfrag,
                                                              (f32x4){0.f, 0.f, 0.f, 0.f}, 0, 0, 0);
            bf16x4 pk;
            for (int r = 0; r < 4; ++r) {
                float p = exp2f(s[r]);
                lsum[r] += p;
                pk[r] = (bf16)p;
            }
            *(bf16x4*)&Pb[w * 16 + l16][((im ^ swz) << 4) + quad * 4] = pk;
        }
    };

    // prologue: S(0) -> P[0]; kf <- K(1)
    bf16x8 kf[4];
    loadK(0, kf);
    computeS(kf, P[0]);
    loadK(1, kf);
    __syncthreads();

    for (int u = 0; u < 63; ++u) {
        const int m0 = u * 64;
        // V(u) fragments (A-operand): c = z*128 + w*32 + i*16 + l16, k = m
        bf16x8 vf[2][2];
        for (int ks = 0; ks < 2; ++ks)
            for (int i = 0; i < 2; ++i)
                vf[ks][i] = *(const bf16x8*)(vbase + (size_t)(i * 16 + l16) * N_ + m0 + ks * 32 + quad * 8);
        // S(u+1) -> P[(u+1)&1] (uses kf = K(u+1)); then reload kf <- K(u+2)
        computeS(kf, P[(u + 1) & 1]);
        loadK(u + 2 < 64 ? u + 2 : 0, kf);
        // PV(u): O += V P^T from P[u&1]
        bf16 (* __restrict__ Pb)[72] = P[u & 1];
        __builtin_amdgcn_s_setprio(1);
        for (int ks = 0; ks < 2; ++ks) {
            bf16x8 pf[4];
            for (int j = 0; j < 4; ++j)
                pf[j] = *(const bf16x8*)&Pb[j * 16 + l16]
                            [((((ks << 1) | (quad >> 1)) ^ swz) << 4) + ((quad & 1) << 3)];
            for (int i = 0; i < 2; ++i)
                for (int j = 0; j < 4; ++j)
                    acc[i][j] = __builtin_amdgcn_mfma_f32_16x16x32_bf16(vf[ks][i], pf[j], acc[i][j], 0, 0, 0);
        }
        __builtin_amdgcn_s_setprio(0);
        __syncthreads();
    }
    // peeled tail: PV(63) from P[1]
    {
        const int m0 = 63 * 64;
        bf16x8 vf[2][2];
        for (int ks = 0; ks < 2; ++ks)
            for (int i = 0; i < 2; ++i)
                vf[ks][i] = *(const bf16x8*)(vbase + (size_t)(i * 16 + l16) * N_ + m0 + ks * 32 + quad * 8);
        bf16 (* __restrict__ Pb)[72] = P[1];
        for (int ks = 0; ks < 2; ++ks) {
            bf16x8 pf[4];
            for (int j = 0; j < 4; ++j)
                pf[j] = *(const bf16x8*)&Pb[j * 16 + l16]
                            [((((ks << 1) | (quad >> 1)) ^ swz) << 4) + ((quad & 1) << 3)];
            for (int i = 0; i < 2; ++i)
                for (int j = 0; j < 4; ++j)
                    acc[i][j] = __builtin_amdgcn_mfma_f32_16x16x32_bf16(vf[ks][i], pf[j], acc[i][j], 0, 0, 0);
        }
    }
    // full softmax denominator (all 64 m-tiles seen in-block); exchange via LDS
    float s = (lsum[0] + lsum[1]) + (lsum[2] + lsum[3]);
    s += __shfl_xor(s, 16);
    s += __shfl_xor(s, 32);
    if (lane < 16) linvs[w * 16 + l16] = 1.f / s;
    __syncthreads();
    float linv[4];
    for (int j = 0; j < 4; ++j) linv[j] = linvs[j * 16 + l16];
    const float g = gamma[0];
    for (int i = 0; i < 2; ++i)
        for (int r = 0; r < 4; ++r) {
            int c = z * 128 + w * 32 + i * 16 + quad * 4 + r;
            for (int j = 0; j < 4; ++j) {
                int n = n0 + j * 16 + l16;
                size_t idx = ((size_t)b * CQ_ + c) * N_ + n;
                out[idx] = g * acc[i][j][r] * linv[j] + query[idx];
            }
        }
}

extern "C" void kernel_launch(void* const* d_in, const int* in_sizes, int n_in,
                              void* d_out, int out_size, void* d_ws, size_t ws_size,
                              hipStream_t stream) {
    const float* query     = (const float*)d_in[0];
    const float* key_value = (const float*)d_in[1];
    const float* Wq = (const float*)d_in[2];
    const float* bq = (const float*)d_in[3];
    const float* Wk = (const float*)d_in[4];
    const float* bk = (const float*)d_in[5];
    const float* Wv = (const float*)d_in[6];
    const float* bv = (const float*)d_in[7];
    const float* gamma = (const float*)d_in[8];
    float* out = (float*)d_out;

    char* ws = (char*)d_ws;
    bf16* kvr  = (bf16*)(ws);              // [8][4096][512]  33,554,432 B
    bf16* vbuf = (bf16*)(ws + 33554432);   // [8][256][4096]  16,777,216 B
    bf16* qTb  = (bf16*)(ws + 50331648);   // [8][4096][32]    2,097,152 B
    bf16* kTb  = (bf16*)(ws + 52428800);   // [8][4096][32]    2,097,152 B
    bf16* wqb  = (bf16*)(ws + 54525952);   // [32][256]           16,384 B
    bf16* wkb  = (bf16*)(ws + 54542336);   // [32][512]           32,768 B
    bf16* wvb  = (bf16*)(ws + 54575104);   // [256][512]         262,144 B

    k_convert_w<<<608, 256, 0, stream>>>(Wq, Wk, Wv, wqb, wkb, wvb);
    k_resize<<<dim3(64, 8, 8), 256, 0, stream>>>(key_value, kvr);
    k_proj_q_fused<<<dim3(64, 8), 256, 0, stream>>>(query, wqb, bq, qTb);
    k_proj_k<<<dim3(128, 8), 256, 0, stream>>>(wkb, bk, kvr, kTb);
    k_proj_v<<<dim3(128, 8), 256, 0, stream>>>(wvb, bv, kvr, vbuf);
    k_flash<<<dim3(64, 8, 2), 256, 0, stream>>>(qTb, kTb, vbuf, query, gamma, out);
}